// Round 1
// baseline (332.934 us; speedup 1.0000x reference)
//
#include <hip/hip_runtime.h>
#include <math.h>

#define B_  2
#define T_  2048
#define D_  512
#define H_  8
#define HD_ 64
#define QKVS (3*D_)   // 1536, row stride of the fused qkv buffer

// ---------------------------------------------------------------------------
// GEMM (NT): C[M,N] = A[M,K] @ B[N,K]^T + bias[N]
// Both A and B are row-major with the dot over contiguous K.
// 64x64 tile, BK=16, 256 threads, 4x4 microtile per thread.
// ---------------------------------------------------------------------------
template<int BM, int BN, int BK>
__global__ __launch_bounds__(256)
void gemm_nt_bias(const float* __restrict__ A, const float* __restrict__ Bm,
                  const float* __restrict__ bias, float* __restrict__ C,
                  int M, int N, int K) {
  __shared__ float As[BK][BM + 4];   // +4 pad: keeps 16B alignment for float4 reads
  __shared__ float Bs[BK][BN + 4];

  const int tid  = threadIdx.x;
  const int tx   = tid & 15;          // col group 0..15
  const int ty   = tid >> 4;          // row group 0..15
  const int lrow = tid >> 2;          // 0..63   (load row within tile)
  const int lcol = (tid & 3) << 2;    // 0,4,8,12 (load col group, float4)
  const int rowbase = blockIdx.y * BM;
  const int colbase = blockIdx.x * BN;

  float acc[4][4] = {};

  const float* Ap = A  + (size_t)(rowbase + lrow) * K + lcol;
  const float* Bp = Bm + (size_t)(colbase + lrow) * K + lcol;

  for (int k0 = 0; k0 < K; k0 += BK) {
    float4 av = *(const float4*)(Ap + k0);
    float4 bv = *(const float4*)(Bp + k0);
    __syncthreads();   // previous iteration done reading LDS
    As[lcol + 0][lrow] = av.x; As[lcol + 1][lrow] = av.y;
    As[lcol + 2][lrow] = av.z; As[lcol + 3][lrow] = av.w;
    Bs[lcol + 0][lrow] = bv.x; Bs[lcol + 1][lrow] = bv.y;
    Bs[lcol + 2][lrow] = bv.z; Bs[lcol + 3][lrow] = bv.w;
    __syncthreads();
    #pragma unroll
    for (int kk = 0; kk < BK; ++kk) {
      float4 af = *(const float4*)(&As[kk][ty << 2]);
      float4 bf = *(const float4*)(&Bs[kk][tx << 2]);
      float a[4] = {af.x, af.y, af.z, af.w};
      float b[4] = {bf.x, bf.y, bf.z, bf.w};
      #pragma unroll
      for (int i2 = 0; i2 < 4; ++i2)
        #pragma unroll
        for (int j2 = 0; j2 < 4; ++j2)
          acc[i2][j2] = fmaf(a[i2], b[j2], acc[i2][j2]);
    }
  }

  float4 bbv = *(const float4*)(bias + colbase + (tx << 2));
  #pragma unroll
  for (int i2 = 0; i2 < 4; ++i2) {
    float4 o;
    o.x = acc[i2][0] + bbv.x;
    o.y = acc[i2][1] + bbv.y;
    o.z = acc[i2][2] + bbv.z;
    o.w = acc[i2][3] + bbv.w;
    *(float4*)(C + (size_t)(rowbase + (ty << 2) + i2) * N + colbase + (tx << 2)) = o;
  }
}

// ---------------------------------------------------------------------------
// Sparse periodic-causal attention.
// Valid keys for query i with period p: j = i - t*p, t = 0..floor(i/p).
// One wave (64 threads) per (b, h, i).
//   Phase A: lanes-as-t, each lane computes a full 64-dim dot (q from LDS
//            broadcast, k row via float4), score -> LDS.
//   Phase B: wave-shuffle max + sum-of-exp softmax over the n valid scores.
//   Phase C: lanes-as-d, coalesced weighted sum over v rows.
// Output layout: ao[(b*T + i)*D + h*HD + d]  (ready for the out-proj GEMM).
// ---------------------------------------------------------------------------
__global__ __launch_bounds__(64)
void attn_sparse(const float* __restrict__ qkv, const int* __restrict__ periods,
                 float* __restrict__ ao) {
  const int idx  = blockIdx.x;
  const int i    = idx & (T_ - 1);
  const int bh   = idx >> 11;          // T_ = 2048 = 2^11
  const int h    = bh & (H_ - 1);
  const int b    = bh >> 3;
  const int lane = threadIdx.x;

  int p = periods[b * H_ + h];
  if (p < 1) p = 1;
  const int n = i / p + 1;             // number of valid keys (>= 1)

  __shared__ float qs[HD_];
  __shared__ float sc[T_];             // up to 2048 scores, 8 KB

  const float* qrow = qkv + (size_t)(b * T_ + i) * QKVS + h * HD_;
  const float* kcol = qkv + (size_t)(b * T_) * QKVS + D_ + h * HD_;
  const float* vcol = qkv + (size_t)(b * T_) * QKVS + 2 * D_ + h * HD_;

  qs[lane] = qrow[lane] * 0.125f;      // fold in 1/sqrt(HD)
  __syncthreads();

  // Phase A: scores
  for (int t = lane; t < n; t += 64) {
    const int j = i - t * p;
    const float* krow = kcol + (size_t)j * QKVS;
    float s = 0.f;
    #pragma unroll
    for (int d = 0; d < HD_; d += 4) {
      float4 kq = *(const float4*)(krow + d);
      float4 qq = *(const float4*)(qs + d);   // same-address LDS broadcast
      s = fmaf(kq.x, qq.x, s);
      s = fmaf(kq.y, qq.y, s);
      s = fmaf(kq.z, qq.z, s);
      s = fmaf(kq.w, qq.w, s);
    }
    sc[t] = s;
  }
  __syncthreads();

  // Phase B: softmax over sc[0..n)
  float m = -INFINITY;
  for (int t = lane; t < n; t += 64) m = fmaxf(m, sc[t]);
  #pragma unroll
  for (int off = 32; off >= 1; off >>= 1) m = fmaxf(m, __shfl_xor(m, off));

  float ssum = 0.f;
  for (int t = lane; t < n; t += 64) {
    float e = __expf(sc[t] - m);
    sc[t] = e;
    ssum += e;
  }
  #pragma unroll
  for (int off = 32; off >= 1; off >>= 1) ssum += __shfl_xor(ssum, off);
  const float inv = 1.f / ssum;
  __syncthreads();

  // Phase C: weighted V accumulation, lane = head-dim element
  float acc = 0.f;
  #pragma unroll 4
  for (int t = 0; t < n; ++t) {
    const int j = i - t * p;
    acc = fmaf(sc[t], vcol[(size_t)j * QKVS + lane], acc);
  }
  ao[(size_t)(b * T_ + i) * D_ + h * HD_ + lane] = acc * inv;
}

// ---------------------------------------------------------------------------
extern "C" void kernel_launch(void* const* d_in, const int* in_sizes, int n_in,
                              void* d_out, int out_size, void* d_ws, size_t ws_size,
                              hipStream_t stream) {
  const float* x      = (const float*)d_in[0];   // (B,T,D)
  const int*   period = (const int*)  d_in[1];   // (B,H)
  const float* w_qkv  = (const float*)d_in[2];   // (3D, D)
  const float* b_qkv  = (const float*)d_in[3];   // (3D,)
  const float* w_out  = (const float*)d_in[4];   // (D, D)
  const float* b_out  = (const float*)d_in[5];   // (D,)
  float* out = (float*)d_out;                    // (B,T,D)

  float* qkv = (float*)d_ws;                       // (B*T, 3D) = 24 MB
  float* ao  = qkv + (size_t)B_ * T_ * QKVS;       // (B*T, D)  =  8 MB

  const int M = B_ * T_;   // 4096

  // 1) QKV projection: (4096,512) @ (1536,512)^T -> (4096,1536)
  gemm_nt_bias<64, 64, 16>
      <<<dim3(QKVS / 64, M / 64), dim3(256), 0, stream>>>(
          x, w_qkv, b_qkv, qkv, M, QKVS, D_);

  // 2) Sparse periodic-causal attention: one wave per (b,h,i)
  attn_sparse<<<dim3(B_ * H_ * T_), dim3(64), 0, stream>>>(qkv, period, ao);

  // 3) Output projection: (4096,512) @ (512,512)^T -> (4096,512)
  gemm_nt_bias<64, 64, 16>
      <<<dim3(D_ / 64, M / 64), dim3(256), 0, stream>>>(
          ao, w_out, b_out, out, M, D_, D_);
}

// Round 2
// 231.605 us; speedup vs baseline: 1.4375x; 1.4375x over previous
//
#include <hip/hip_runtime.h>
#include <math.h>

#define B_  2
#define T_  2048
#define D_  512
#define H_  8
#define HD_ 64
#define QKVS (3*D_)   // 1536, row stride of fused qkv buffer

typedef __bf16 bf16x8 __attribute__((ext_vector_type(8)));
typedef float  f32x4  __attribute__((ext_vector_type(4)));

__device__ inline unsigned short f2bf(float f) {   // RN-even fp32->bf16
  unsigned int u = __float_as_uint(f);
  return (unsigned short)((u + 0x7FFFu + ((u >> 16) & 1u)) >> 16);
}

// ---------------------------------------------------------------------------
// cast fp32 -> bf16, 4 elements/thread
// ---------------------------------------------------------------------------
__global__ void cast_f32_bf16(const float* __restrict__ src,
                              unsigned short* __restrict__ dst, int n4) {
  int i = blockIdx.x * blockDim.x + threadIdx.x;
  if (i < n4) {
    float4 v = ((const float4*)src)[i];
    ushort4 o;
    o.x = f2bf(v.x); o.y = f2bf(v.y); o.z = f2bf(v.z); o.w = f2bf(v.w);
    ((ushort4*)dst)[i] = o;
  }
}

// ---------------------------------------------------------------------------
// MFMA bf16 GEMM (NT): C[M,N] = A[M,K] @ B[N,K]^T + bias[N], C fp32.
// BM=128, BN=64, BK=32. 256 threads = 4 waves; wave (wr=w>>1, wc=w&1)
// computes a 64x32 subtile as 4x2 accs of 16x16x32 MFMAs.
// Staging via global_load_lds width=16 (wave-uniform LDS base + lane*16).
// ---------------------------------------------------------------------------
__global__ __launch_bounds__(256)
void gemm_nt_mfma(const unsigned short* __restrict__ A,
                  const unsigned short* __restrict__ Bw,
                  const float* __restrict__ bias, float* __restrict__ C,
                  int M, int N, int K) {
  __shared__ short Asd[128 * 32];   // [row][k] row-major, 8 KB
  __shared__ short Bsd[64 * 32];    // [col][k] row-major, 4 KB

  const int tid = threadIdx.x;
  const int w   = tid >> 6;         // wave 0..3
  const int l   = tid & 63;         // lane
  const int wr  = w >> 1;           // wave row 0..1 (64-row halves)
  const int wc  = w & 1;            // wave col 0..1 (32-col halves)
  const int q   = l >> 4;           // quad 0..3
  const int ml  = l & 15;
  const int arow = l >> 2;          // 0..15: staging row within 16-row chunk
  const int kch  = (l & 3) * 8;     // staging k-offset (elements)

  const int rowbase = blockIdx.y * 128;
  const int colbase = blockIdx.x * 64;

  f32x4 acc[4][2] = {};

  for (int k0 = 0; k0 < K; k0 += 32) {
    __syncthreads();   // LDS free (previous iter's reads done)
    // A-tile: 128 rows x 32 k = 8 KB -> 2 issues of (4 waves x 1 KB)
    #pragma unroll
    for (int s = 0; s < 2; ++s) {
      const unsigned short* g =
          A + (size_t)(rowbase + s * 64 + w * 16 + arow) * K + k0 + kch;
      short* lp = &Asd[s * 2048 + w * 512];   // wave-uniform base
      __builtin_amdgcn_global_load_lds(
          (const __attribute__((address_space(1))) void*)g,
          (__attribute__((address_space(3))) void*)lp, 16, 0, 0);
    }
    // B-tile: 64 rows x 32 k = 4 KB -> 1 issue
    {
      const unsigned short* g =
          Bw + (size_t)(colbase + w * 16 + arow) * K + k0 + kch;
      short* lp = &Bsd[w * 512];
      __builtin_amdgcn_global_load_lds(
          (const __attribute__((address_space(1))) void*)g,
          (__attribute__((address_space(3))) void*)lp, 16, 0, 0);
    }
    __syncthreads();   // drains vmcnt -> LDS valid

    bf16x8 af[4], bfr[2];
    #pragma unroll
    for (int mi = 0; mi < 4; ++mi)
      af[mi] = *(const bf16x8*)&Asd[(wr * 64 + mi * 16 + ml) * 32 + q * 8];
    #pragma unroll
    for (int ni = 0; ni < 2; ++ni)
      bfr[ni] = *(const bf16x8*)&Bsd[(wc * 32 + ni * 16 + ml) * 32 + q * 8];
    #pragma unroll
    for (int mi = 0; mi < 4; ++mi)
      #pragma unroll
      for (int ni = 0; ni < 2; ++ni)
        acc[mi][ni] = __builtin_amdgcn_mfma_f32_16x16x32_bf16(
            af[mi], bfr[ni], acc[mi][ni], 0, 0, 0);
  }

  // Epilogue: D[row=q*4+r][col=ml] per acc; add bias, store fp32.
  #pragma unroll
  for (int mi = 0; mi < 4; ++mi) {
    #pragma unroll
    for (int ni = 0; ni < 2; ++ni) {
      const int col = colbase + wc * 32 + ni * 16 + ml;
      const float bv = bias[col];
      #pragma unroll
      for (int r = 0; r < 4; ++r) {
        const int row = rowbase + wr * 64 + mi * 16 + q * 4 + r;
        C[(size_t)row * N + col] = acc[mi][ni][r] + bv;
      }
    }
  }
}

// ---------------------------------------------------------------------------
// Sparse periodic-causal attention (unchanged from R1 except bf16 output).
// One wave per (b, h, i); valid keys j = i - t*p.
// ---------------------------------------------------------------------------
__global__ __launch_bounds__(64)
void attn_sparse(const float* __restrict__ qkv, const int* __restrict__ periods,
                 unsigned short* __restrict__ aob) {
  const int idx  = blockIdx.x;
  const int i    = idx & (T_ - 1);
  const int bh   = idx >> 11;
  const int h    = bh & (H_ - 1);
  const int b    = bh >> 3;
  const int lane = threadIdx.x;

  int p = periods[b * H_ + h];
  if (p < 1) p = 1;
  const int n = i / p + 1;

  __shared__ float qs[HD_];
  __shared__ float sc[T_];

  const float* qrow = qkv + (size_t)(b * T_ + i) * QKVS + h * HD_;
  const float* kcol = qkv + (size_t)(b * T_) * QKVS + D_ + h * HD_;
  const float* vcol = qkv + (size_t)(b * T_) * QKVS + 2 * D_ + h * HD_;

  qs[lane] = qrow[lane] * 0.125f;
  __syncthreads();

  for (int t = lane; t < n; t += 64) {
    const int j = i - t * p;
    const float* krow = kcol + (size_t)j * QKVS;
    float s = 0.f;
    #pragma unroll
    for (int d = 0; d < HD_; d += 4) {
      float4 kq = *(const float4*)(krow + d);
      float4 qq = *(const float4*)(qs + d);
      s = fmaf(kq.x, qq.x, s);
      s = fmaf(kq.y, qq.y, s);
      s = fmaf(kq.z, qq.z, s);
      s = fmaf(kq.w, qq.w, s);
    }
    sc[t] = s;
  }
  __syncthreads();

  float m = -INFINITY;
  for (int t = lane; t < n; t += 64) m = fmaxf(m, sc[t]);
  #pragma unroll
  for (int off = 32; off >= 1; off >>= 1) m = fmaxf(m, __shfl_xor(m, off));

  float ssum = 0.f;
  for (int t = lane; t < n; t += 64) {
    float e = __expf(sc[t] - m);
    sc[t] = e;
    ssum += e;
  }
  #pragma unroll
  for (int off = 32; off >= 1; off >>= 1) ssum += __shfl_xor(ssum, off);
  const float inv = 1.f / ssum;
  __syncthreads();

  float acc = 0.f;
  #pragma unroll 4
  for (int t = 0; t < n; ++t) {
    const int j = i - t * p;
    acc = fmaf(sc[t], vcol[(size_t)j * QKVS + lane], acc);
  }
  aob[(size_t)(b * T_ + i) * D_ + h * HD_ + lane] = f2bf(acc * inv);
}

// ---------------------------------------------------------------------------
extern "C" void kernel_launch(void* const* d_in, const int* in_sizes, int n_in,
                              void* d_out, int out_size, void* d_ws, size_t ws_size,
                              hipStream_t stream) {
  const float* x      = (const float*)d_in[0];   // (B,T,D)
  const int*   period = (const int*)  d_in[1];   // (B,H)
  const float* w_qkv  = (const float*)d_in[2];   // (3D, D)
  const float* b_qkv  = (const float*)d_in[3];   // (3D,)
  const float* w_out  = (const float*)d_in[4];   // (D, D)
  const float* b_out  = (const float*)d_in[5];   // (D,)
  float* out = (float*)d_out;                    // (B,T,D)

  const int M = B_ * T_;                         // 4096

  // Workspace layout (bytes):
  //   [0,        4 MB)  xb  (x bf16)  -- reused as aob after GEMM1
  //   [4 MB,   5.5 MB)  wqb (w_qkv bf16)
  //   [5.5 MB,   6 MB)  wob (w_out bf16)
  //   [6 MB,    30 MB)  qkv fp32 (4096 x 1536)
  char* ws = (char*)d_ws;
  unsigned short* xb  = (unsigned short*)(ws + 0);
  unsigned short* wqb = (unsigned short*)(ws + (size_t)M * D_ * 2);            // +4 MB
  unsigned short* wob = (unsigned short*)(ws + (size_t)M * D_ * 2
                                             + (size_t)QKVS * D_ * 2);         // +5.5 MB
  float* qkv = (float*)(ws + (size_t)M * D_ * 2 + (size_t)QKVS * D_ * 2
                           + (size_t)D_ * D_ * 2);                             // +6 MB
  unsigned short* aob = xb;   // alias: x_bf16 dead after GEMM1

  // casts
  cast_f32_bf16<<<dim3((M * D_ / 4 + 255) / 256), dim3(256), 0, stream>>>(
      x, xb, M * D_ / 4);
  cast_f32_bf16<<<dim3((QKVS * D_ / 4 + 255) / 256), dim3(256), 0, stream>>>(
      w_qkv, wqb, QKVS * D_ / 4);
  cast_f32_bf16<<<dim3((D_ * D_ / 4 + 255) / 256), dim3(256), 0, stream>>>(
      w_out, wob, D_ * D_ / 4);

  // 1) QKV projection: (4096,512) @ (1536,512)^T -> (4096,1536) fp32
  gemm_nt_mfma<<<dim3(QKVS / 64, M / 128), dim3(256), 0, stream>>>(
      xb, wqb, b_qkv, qkv, M, QKVS, D_);

  // 2) sparse periodic-causal attention -> aob (bf16)
  attn_sparse<<<dim3(B_ * H_ * T_), dim3(64), 0, stream>>>(qkv, period, aob);

  // 3) output projection: (4096,512) @ (512,512)^T -> (4096,512) fp32
  gemm_nt_mfma<<<dim3(D_ / 64, M / 128), dim3(256), 0, stream>>>(
      aob, wob, b_out, out, M, D_, D_);
}

// Round 3
// 213.146 us; speedup vs baseline: 1.5620x; 1.0866x over previous
//
#include <hip/hip_runtime.h>
#include <math.h>

#define B_  2
#define T_  2048
#define D_  512
#define H_  8
#define HD_ 64
#define QKVS (3*D_)   // 1536 halfs, row stride of fused qkv buffer

typedef __bf16 bf16x8 __attribute__((ext_vector_type(8)));
typedef float  f32x4  __attribute__((ext_vector_type(4)));

__device__ inline unsigned short f2bf(float f) {   // RN-even fp32->bf16
  unsigned int u = __float_as_uint(f);
  return (unsigned short)((u + 0x7FFFu + ((u >> 16) & 1u)) >> 16);
}
__device__ inline unsigned int pack2bf(float lo, float hi) {
  return (unsigned int)f2bf(lo) | ((unsigned int)f2bf(hi) << 16);
}

// ---------------------------------------------------------------------------
// cast fp32 -> bf16, 4 elements/thread
// ---------------------------------------------------------------------------
__global__ void cast_f32_bf16(const float* __restrict__ src,
                              unsigned short* __restrict__ dst, int n4) {
  int i = blockIdx.x * blockDim.x + threadIdx.x;
  if (i < n4) {
    float4 v = ((const float4*)src)[i];
    ushort4 o;
    o.x = f2bf(v.x); o.y = f2bf(v.y); o.z = f2bf(v.z); o.w = f2bf(v.w);
    ((ushort4*)dst)[i] = o;
  }
}

// ---------------------------------------------------------------------------
// MFMA bf16 GEMM (NT): C[M,N] = A[M,K] @ B[N,K]^T + bias[N].
// BM=128, BN=64, BK=32; 256 threads = 4 waves; per-wave 64x32 = 4x2 MFMA accs.
// BF16OUT=1 -> C stored bf16 (u16), else fp32.
// ---------------------------------------------------------------------------
template<int BF16OUT>
__global__ __launch_bounds__(256)
void gemm_nt_mfma(const unsigned short* __restrict__ A,
                  const unsigned short* __restrict__ Bw,
                  const float* __restrict__ bias, void* __restrict__ Cv,
                  int M, int N, int K) {
  __shared__ short Asd[128 * 32];
  __shared__ short Bsd[64 * 32];

  const int tid = threadIdx.x;
  const int w   = tid >> 6;
  const int l   = tid & 63;
  const int wr  = w >> 1;
  const int wc  = w & 1;
  const int q   = l >> 4;
  const int ml  = l & 15;
  const int arow = l >> 2;
  const int kch  = (l & 3) * 8;

  const int rowbase = blockIdx.y * 128;
  const int colbase = blockIdx.x * 64;

  f32x4 acc[4][2] = {};

  for (int k0 = 0; k0 < K; k0 += 32) {
    __syncthreads();
    #pragma unroll
    for (int s = 0; s < 2; ++s) {
      const unsigned short* g =
          A + (size_t)(rowbase + s * 64 + w * 16 + arow) * K + k0 + kch;
      short* lp = &Asd[s * 2048 + w * 512];
      __builtin_amdgcn_global_load_lds(
          (const __attribute__((address_space(1))) void*)g,
          (__attribute__((address_space(3))) void*)lp, 16, 0, 0);
    }
    {
      const unsigned short* g =
          Bw + (size_t)(colbase + w * 16 + arow) * K + k0 + kch;
      short* lp = &Bsd[w * 512];
      __builtin_amdgcn_global_load_lds(
          (const __attribute__((address_space(1))) void*)g,
          (__attribute__((address_space(3))) void*)lp, 16, 0, 0);
    }
    __syncthreads();

    bf16x8 af[4], bfr[2];
    #pragma unroll
    for (int mi = 0; mi < 4; ++mi)
      af[mi] = *(const bf16x8*)&Asd[(wr * 64 + mi * 16 + ml) * 32 + q * 8];
    #pragma unroll
    for (int ni = 0; ni < 2; ++ni)
      bfr[ni] = *(const bf16x8*)&Bsd[(wc * 32 + ni * 16 + ml) * 32 + q * 8];
    #pragma unroll
    for (int mi = 0; mi < 4; ++mi)
      #pragma unroll
      for (int ni = 0; ni < 2; ++ni)
        acc[mi][ni] = __builtin_amdgcn_mfma_f32_16x16x32_bf16(
            af[mi], bfr[ni], acc[mi][ni], 0, 0, 0);
  }

  #pragma unroll
  for (int mi = 0; mi < 4; ++mi) {
    #pragma unroll
    for (int ni = 0; ni < 2; ++ni) {
      const int col = colbase + wc * 32 + ni * 16 + ml;
      const float bv = bias[col];
      #pragma unroll
      for (int r = 0; r < 4; ++r) {
        const int row = rowbase + wr * 64 + mi * 16 + q * 4 + r;
        const float val = acc[mi][ni][r] + bv;
        if (BF16OUT)
          ((unsigned short*)Cv)[(size_t)row * N + col] = f2bf(val);
        else
          ((float*)Cv)[(size_t)row * N + col] = val;
      }
    }
  }
}

// ---------------------------------------------------------------------------
// Worklist builder: one lane per (b,h). Items = (residue r, q-tile g),
// emitted heavy-first (descending g). Fixed stride 192 per head, sentinel-pad.
// ---------------------------------------------------------------------------
__global__ void build_worklist(const int* __restrict__ periods,
                               unsigned int* __restrict__ wl) {
  const int lane = threadIdx.x;
  if (lane >= 16) return;
  int p = periods[lane]; if (p < 1) p = 1;
  int Tr[64];
  int G = 0;
  for (int r = 0; r < p; ++r) {
    int L = (T_ - 1 - r) / p + 1;          // # tokens with residue r
    int t = (L + 15) >> 4;                 // 16-query tiles
    Tr[r] = t;
    if (t > G) G = t;
  }
  int pos = 0;
  for (int g = G - 1; g >= 0; --g)
    for (int r = 0; r < p; ++r)
      if (g < Tr[r])
        wl[(pos++) * 16 + lane] =
            ((unsigned)lane << 16) | ((unsigned)r << 8) | (unsigned)g;
  for (; pos < 192; ++pos) wl[pos * 16 + lane] = 0xFFFFFFFFu;
}

// ---------------------------------------------------------------------------
// Residue-class flash attention. One wave per (bh, r, q-tile of 16).
// Subsequence tokens: g(t) = r + t*p. Dense causal over t.
//  S^T = K_tile(32xHD) . Q^T(HDx16)  via mfma 16x16x32 (A=K, B=Q^T)
//    C-layout: row = key = quad*4+reg, col = q = lane&15  -> softmax per col,
//    m/l/alpha live per-lane (q = c), no shuffles for rescale.
//  P^T: C-layout -> B-operand layout via 8 __shfl + 4 selects (no LDS trip).
//  O^T += V^T . P^T   (A = V^T read as u16 gathers from row-major V tile).
//  O^T C-layout: row = d = quad*4+reg (+16*chunk), col = q = lane&15.
// ---------------------------------------------------------------------------
__global__ __launch_bounds__(64)
void attn_flash(const unsigned short* __restrict__ qkv,
                const int* __restrict__ periods,
                const unsigned int* __restrict__ wl,
                unsigned short* __restrict__ ao) {
  const unsigned int wv = wl[blockIdx.y * 16 + blockIdx.x];
  if (wv == 0xFFFFFFFFu) return;
  const int bh = wv >> 16, r = (wv >> 8) & 0xFF, qt = wv & 0xFF;
  const int b = bh >> 3, h = bh & 7;
  int p = periods[bh]; if (p < 1) p = 1;
  const int L  = (T_ - 1 - r) / p + 1;
  const int q0 = qt << 4;
  const int nq = min(16, L - q0);
  const int Nk = min(L, q0 + 16);          // keys needed by this q-tile

  const int lane = threadIdx.x;
  const int Q = lane >> 4, c = lane & 15;

  __shared__ unsigned short Qs[16 * 72];   // stride 72 halfs (144 B, 16B-aligned)
  __shared__ unsigned short Ks[32 * 72];
  __shared__ unsigned short Vs[32 * 70];   // stride 70 (b32 writes; u16 reads conflict-free)

  const size_t rowb = (size_t)b * T_ * QKVS + (size_t)h * HD_;

  // ---- stage Q tile (16 rows x 64 halfs), 2 b128 per lane ----
  {
    const int u = lane >> 2, ch3 = lane & 3;
    const int t = q0 + min(u, nq - 1);     // clamp (dup row; unused cols masked)
    const unsigned short* g = qkv + rowb + (size_t)(r + t * p) * QKVS + ch3 * 16;
    int4 v0 = ((const int4*)g)[0];
    int4 v1 = ((const int4*)g)[1];
    *(int4*)&Qs[u * 72 + ch3 * 16 + 0] = v0;
    *(int4*)&Qs[u * 72 + ch3 * 16 + 8] = v1;
  }
  __syncthreads();
  bf16x8 qf[2];                            // B-frag: B[k=d=Q*8+j+32hf][n=q=c]
  qf[0] = *(const bf16x8*)&Qs[c * 72 + Q * 8];
  qf[1] = *(const bf16x8*)&Qs[c * 72 + Q * 8 + 32];

  float m_run = -3.0e38f, l_run = 0.f;
  f32x4 o[4] = {};
  const size_t kb = rowb + D_;
  const size_t vb = rowb + 2 * D_;
  const int kap = lane >> 1, ke = lane & 1;

  for (int k0 = 0; k0 < Nk; k0 += 32) {
    // ---- stage K,V tile (32 rows x 64 halfs each) ----
    {
      const int t = min(k0 + kap, Nk - 1); // clamp (dups masked by causal cond)
      const unsigned short* gk = qkv + kb + (size_t)(r + t * p) * QKVS + ke * 32;
      const unsigned short* gv = qkv + vb + (size_t)(r + t * p) * QKVS + ke * 32;
      int4 a0 = ((const int4*)gk)[0], a1 = ((const int4*)gk)[1],
           a2 = ((const int4*)gk)[2], a3 = ((const int4*)gk)[3];
      int4 b0 = ((const int4*)gv)[0], b1 = ((const int4*)gv)[1],
           b2 = ((const int4*)gv)[2], b3 = ((const int4*)gv)[3];
      __syncthreads();                     // prev iter's frag reads complete
      *(int4*)&Ks[kap * 72 + ke * 32 + 0]  = a0;
      *(int4*)&Ks[kap * 72 + ke * 32 + 8]  = a1;
      *(int4*)&Ks[kap * 72 + ke * 32 + 16] = a2;
      *(int4*)&Ks[kap * 72 + ke * 32 + 24] = a3;
      unsigned int* vw = (unsigned int*)Vs + kap * 35 + ke * 16;
      int4 bb[4] = {b0, b1, b2, b3};
      #pragma unroll
      for (int i = 0; i < 4; ++i) {
        vw[i * 4 + 0] = bb[i].x; vw[i * 4 + 1] = bb[i].y;
        vw[i * 4 + 2] = bb[i].z; vw[i * 4 + 3] = bb[i].w;
      }
      __syncthreads();
    }

    // ---- S^T = K . Q^T  (two 16-key M-tiles, K-depth 64 = 2 chained) ----
    f32x4 s[2];
    #pragma unroll
    for (int mt = 0; mt < 2; ++mt) {
      bf16x8 a0 = *(const bf16x8*)&Ks[(mt * 16 + c) * 72 + Q * 8];
      bf16x8 a1 = *(const bf16x8*)&Ks[(mt * 16 + c) * 72 + Q * 8 + 32];
      f32x4 acc = {};
      acc = __builtin_amdgcn_mfma_f32_16x16x32_bf16(a0, qf[0], acc, 0, 0, 0);
      acc = __builtin_amdgcn_mfma_f32_16x16x32_bf16(a1, qf[1], acc, 0, 0, 0);
      s[mt] = acc;
    }

    // ---- scale + causal mask + online softmax (per col q=c) ----
    float pvv[8];
    float tmax = -3.0e38f;
    #pragma unroll
    for (int mt = 0; mt < 2; ++mt)
      #pragma unroll
      for (int rg = 0; rg < 4; ++rg) {
        const int kk = k0 + mt * 16 + Q * 4 + rg;   // key t-index
        float v = s[mt][rg] * 0.125f;               // 1/sqrt(HD)
        v = (kk <= q0 + c) ? v : -3.0e38f;          // causal in t-space
        pvv[mt * 4 + rg] = v;
        tmax = fmaxf(tmax, v);
      }
    tmax = fmaxf(tmax, __shfl_xor(tmax, 16));
    tmax = fmaxf(tmax, __shfl_xor(tmax, 32));
    const float m_new = fmaxf(m_run, tmax);
    const float alpha = __expf(m_run - m_new);
    float tsum = 0.f;
    #pragma unroll
    for (int i = 0; i < 8; ++i) { pvv[i] = __expf(pvv[i] - m_new); tsum += pvv[i]; }
    tsum += __shfl_xor(tsum, 16);
    tsum += __shfl_xor(tsum, 32);
    l_run = l_run * alpha + tsum;
    m_run = m_new;

    // ---- P^T: C-layout -> B-operand layout (8 shfl + 4 selects) ----
    unsigned int pk0[2], pk1[2];
    pk0[0] = pack2bf(pvv[0], pvv[1]); pk0[1] = pack2bf(pvv[2], pvv[3]);
    pk1[0] = pack2bf(pvv[4], pvv[5]); pk1[1] = pack2bf(pvv[6], pvv[7]);
    int dw[4];
    const int sq2 = (Q & 1) << 1;
    #pragma unroll
    for (int d = 0; d < 4; ++d) {
      const int src = ((sq2 + (d >> 1)) << 4) + c;
      const int v0 = __shfl((int)pk0[d & 1], src);
      const int v1 = __shfl((int)pk1[d & 1], src);
      dw[d] = (Q >= 2) ? v1 : v0;
    }
    int4 bi = make_int4(dw[0], dw[1], dw[2], dw[3]);
    bf16x8 pb = *(bf16x8*)&bi;

    // ---- O^T += V^T . P^T  (4 d-chunks of 16) ----
    #pragma unroll
    for (int ch = 0; ch < 4; ++ch) {
      unsigned short vh[8];
      #pragma unroll
      for (int j = 0; j < 8; ++j)
        vh[j] = Vs[(Q * 8 + j) * 70 + ch * 16 + c];
      unsigned int vi[4];
      #pragma unroll
      for (int j = 0; j < 4; ++j)
        vi[j] = (unsigned int)vh[2 * j] | ((unsigned int)vh[2 * j + 1] << 16);
      int4 ai4 = make_int4((int)vi[0], (int)vi[1], (int)vi[2], (int)vi[3]);
      bf16x8 af = *(bf16x8*)&ai4;
      f32x4 oo = o[ch];
      #pragma unroll
      for (int t2 = 0; t2 < 4; ++t2) oo[t2] *= alpha;
      o[ch] = __builtin_amdgcn_mfma_f32_16x16x32_bf16(af, pb, oo, 0, 0, 0);
    }
  }

  // ---- epilogue: O[q][d] = O^T[d][q] / l ----
  if (c < nq) {
    const float invl = 1.f / l_run;
    const int gq = r + (q0 + c) * p;
    unsigned int* dst =
        (unsigned int*)(ao + (size_t)(b * T_ + gq) * D_ + h * HD_);
    #pragma unroll
    for (int ch = 0; ch < 4; ++ch)
      #pragma unroll
      for (int rp = 0; rp < 2; ++rp) {
        const int dhalf = ch * 16 + Q * 4 + rp * 2;   // even
        dst[dhalf >> 1] =
            pack2bf(o[ch][rp * 2] * invl, o[ch][rp * 2 + 1] * invl);
      }
  }
}

// ---------------------------------------------------------------------------
extern "C" void kernel_launch(void* const* d_in, const int* in_sizes, int n_in,
                              void* d_out, int out_size, void* d_ws, size_t ws_size,
                              hipStream_t stream) {
  const float* x      = (const float*)d_in[0];   // (B,T,D)
  const int*   period = (const int*)  d_in[1];   // (B,H)
  const float* w_qkv  = (const float*)d_in[2];   // (3D, D)
  const float* b_qkv  = (const float*)d_in[3];   // (3D,)
  const float* w_out  = (const float*)d_in[4];   // (D, D)
  const float* b_out  = (const float*)d_in[5];   // (D,)
  float* out = (float*)d_out;                    // (B,T,D)

  const int M = B_ * T_;                         // 4096

  // ws layout (bytes):
  //   [0,    4 MB) xb (x bf16)         -- reused as aob after GEMM1
  //   [4,  5.5 MB) wqb (w_qkv bf16)
  //   [5.5,  6 MB) wob (w_out bf16)
  //   [6,   18 MB) qkvb bf16 (4096 x 1536)
  //   [18MB, +12K) worklist (192*16 u32)
  char* ws = (char*)d_ws;
  unsigned short* xb   = (unsigned short*)(ws);
  unsigned short* wqb  = (unsigned short*)(ws + (size_t)M * D_ * 2);
  unsigned short* wob  = (unsigned short*)(ws + (size_t)M * D_ * 2
                                              + (size_t)QKVS * D_ * 2);
  unsigned short* qkvb = (unsigned short*)(ws + (size_t)M * D_ * 2
                                              + (size_t)QKVS * D_ * 2
                                              + (size_t)D_ * D_ * 2);
  unsigned int*   wl   = (unsigned int*)((char*)qkvb + (size_t)M * QKVS * 2);
  unsigned short* aob  = xb;   // alias: x_bf16 dead after GEMM1

  // input casts
  cast_f32_bf16<<<dim3((M * D_ / 4 + 255) / 256), dim3(256), 0, stream>>>(
      x, xb, M * D_ / 4);
  cast_f32_bf16<<<dim3((QKVS * D_ / 4 + 255) / 256), dim3(256), 0, stream>>>(
      w_qkv, wqb, QKVS * D_ / 4);
  cast_f32_bf16<<<dim3((D_ * D_ / 4 + 255) / 256), dim3(256), 0, stream>>>(
      w_out, wob, D_ * D_ / 4);

  // worklist (16 lanes in one block)
  build_worklist<<<dim3(1), dim3(64), 0, stream>>>(period, wl);

  // 1) QKV projection -> bf16 qkv
  gemm_nt_mfma<1><<<dim3(QKVS / 64, M / 128), dim3(256), 0, stream>>>(
      xb, wqb, b_qkv, qkvb, M, QKVS, D_);

  // 2) residue-class flash attention -> aob (bf16)
  attn_flash<<<dim3(16, 192), dim3(64), 0, stream>>>(qkvb, period, wl, aob);

  // 3) output projection -> fp32 out
  gemm_nt_mfma<0><<<dim3(D_ / 64, M / 128), dim3(256), 0, stream>>>(
      aob, wob, b_out, out, M, D_, D_);
}

// Round 4
// 125.585 us; speedup vs baseline: 2.6511x; 1.6972x over previous
//
#include <hip/hip_runtime.h>
#include <math.h>

#define B_  2
#define T_  2048
#define D_  512
#define H_  8
#define HD_ 64
#define QKVS (3*D_)   // 1536 halfs, row stride of fused qkv buffer

typedef __bf16 bf16x8 __attribute__((ext_vector_type(8)));
typedef float  f32x4  __attribute__((ext_vector_type(4)));

__device__ inline unsigned short f2bf(float f) {   // RN-even fp32->bf16
  unsigned int u = __float_as_uint(f);
  return (unsigned short)((u + 0x7FFFu + ((u >> 16) & 1u)) >> 16);
}
__device__ inline unsigned int pack2bf(float lo, float hi) {
  return (unsigned int)f2bf(lo) | ((unsigned int)f2bf(hi) << 16);
}

// ---------------------------------------------------------------------------
// cast fp32 -> bf16, 4 elements/thread
// ---------------------------------------------------------------------------
__global__ void cast_f32_bf16(const float* __restrict__ src,
                              unsigned short* __restrict__ dst, int n4) {
  int i = blockIdx.x * blockDim.x + threadIdx.x;
  if (i < n4) {
    float4 v = ((const float4*)src)[i];
    ushort4 o;
    o.x = f2bf(v.x); o.y = f2bf(v.y); o.z = f2bf(v.z); o.w = f2bf(v.w);
    ((ushort4*)dst)[i] = o;
  }
}

// ---------------------------------------------------------------------------
// MFMA bf16 GEMM (NT), 128x64 tile: 4 waves, each 64x32 = 4x2 accs.
// Used for the out-projection (N=512 -> grid 256 = 1 block/CU, balanced).
// ---------------------------------------------------------------------------
template<int BF16OUT>
__global__ __launch_bounds__(256)
void gemm_nt_mfma(const unsigned short* __restrict__ A,
                  const unsigned short* __restrict__ Bw,
                  const float* __restrict__ bias, void* __restrict__ Cv,
                  int M, int N, int K) {
  __shared__ short Asd[128 * 32];
  __shared__ short Bsd[64 * 32];

  const int tid = threadIdx.x;
  const int w   = tid >> 6;
  const int l   = tid & 63;
  const int wr  = w >> 1;
  const int wc  = w & 1;
  const int q   = l >> 4;
  const int ml  = l & 15;
  const int arow = l >> 2;
  const int kch  = (l & 3) * 8;

  const int rowbase = blockIdx.y * 128;
  const int colbase = blockIdx.x * 64;

  f32x4 acc[4][2] = {};

  for (int k0 = 0; k0 < K; k0 += 32) {
    __syncthreads();
    #pragma unroll
    for (int s = 0; s < 2; ++s) {
      const unsigned short* g =
          A + (size_t)(rowbase + s * 64 + w * 16 + arow) * K + k0 + kch;
      short* lp = &Asd[s * 2048 + w * 512];
      __builtin_amdgcn_global_load_lds(
          (const __attribute__((address_space(1))) void*)g,
          (__attribute__((address_space(3))) void*)lp, 16, 0, 0);
    }
    {
      const unsigned short* g =
          Bw + (size_t)(colbase + w * 16 + arow) * K + k0 + kch;
      short* lp = &Bsd[w * 512];
      __builtin_amdgcn_global_load_lds(
          (const __attribute__((address_space(1))) void*)g,
          (__attribute__((address_space(3))) void*)lp, 16, 0, 0);
    }
    __syncthreads();

    bf16x8 af[4], bfr[2];
    #pragma unroll
    for (int mi = 0; mi < 4; ++mi)
      af[mi] = *(const bf16x8*)&Asd[(wr * 64 + mi * 16 + ml) * 32 + q * 8];
    #pragma unroll
    for (int ni = 0; ni < 2; ++ni)
      bfr[ni] = *(const bf16x8*)&Bsd[(wc * 32 + ni * 16 + ml) * 32 + q * 8];
    #pragma unroll
    for (int mi = 0; mi < 4; ++mi)
      #pragma unroll
      for (int ni = 0; ni < 2; ++ni)
        acc[mi][ni] = __builtin_amdgcn_mfma_f32_16x16x32_bf16(
            af[mi], bfr[ni], acc[mi][ni], 0, 0, 0);
  }

  #pragma unroll
  for (int mi = 0; mi < 4; ++mi) {
    #pragma unroll
    for (int ni = 0; ni < 2; ++ni) {
      const int col = colbase + wc * 32 + ni * 16 + ml;
      const float bv = bias[col];
      #pragma unroll
      for (int r = 0; r < 4; ++r) {
        const int row = rowbase + wr * 64 + mi * 16 + q * 4 + r;
        const float val = acc[mi][ni][r] + bv;
        if (BF16OUT)
          ((unsigned short*)Cv)[(size_t)row * N + col] = f2bf(val);
        else
          ((float*)Cv)[(size_t)row * N + col] = val;
      }
    }
  }
}

// ---------------------------------------------------------------------------
// MFMA bf16 GEMM (NT), 128x128 tile: 4 waves (2x2), each 64x64 = 4x4 accs.
// Double MFMA density per staged byte vs the 128x64 kernel. Used for QKV.
// ---------------------------------------------------------------------------
template<int BF16OUT>
__global__ __launch_bounds__(256)
void gemm_nt_mfma128(const unsigned short* __restrict__ A,
                     const unsigned short* __restrict__ Bw,
                     const float* __restrict__ bias, void* __restrict__ Cv,
                     int M, int N, int K) {
  __shared__ short Asd[128 * 32];   // 8 KB
  __shared__ short Bsd[128 * 32];   // 8 KB

  const int tid = threadIdx.x;
  const int w   = tid >> 6;
  const int l   = tid & 63;
  const int wr  = w >> 1;           // wave row 0..1 (64-row halves)
  const int wc  = w & 1;            // wave col 0..1 (64-col halves)
  const int q   = l >> 4;
  const int ml  = l & 15;
  const int arow = l >> 2;
  const int kch  = (l & 3) * 8;

  const int rowbase = blockIdx.y * 128;
  const int colbase = blockIdx.x * 128;

  f32x4 acc[4][4] = {};

  for (int k0 = 0; k0 < K; k0 += 32) {
    __syncthreads();
    #pragma unroll
    for (int s = 0; s < 2; ++s) {
      const unsigned short* ga =
          A + (size_t)(rowbase + s * 64 + w * 16 + arow) * K + k0 + kch;
      __builtin_amdgcn_global_load_lds(
          (const __attribute__((address_space(1))) void*)ga,
          (__attribute__((address_space(3))) void*)&Asd[s * 2048 + w * 512],
          16, 0, 0);
      const unsigned short* gb =
          Bw + (size_t)(colbase + s * 64 + w * 16 + arow) * K + k0 + kch;
      __builtin_amdgcn_global_load_lds(
          (const __attribute__((address_space(1))) void*)gb,
          (__attribute__((address_space(3))) void*)&Bsd[s * 2048 + w * 512],
          16, 0, 0);
    }
    __syncthreads();

    bf16x8 af[4], bfr[4];
    #pragma unroll
    for (int mi = 0; mi < 4; ++mi)
      af[mi] = *(const bf16x8*)&Asd[(wr * 64 + mi * 16 + ml) * 32 + q * 8];
    #pragma unroll
    for (int ni = 0; ni < 4; ++ni)
      bfr[ni] = *(const bf16x8*)&Bsd[(wc * 64 + ni * 16 + ml) * 32 + q * 8];
    #pragma unroll
    for (int mi = 0; mi < 4; ++mi)
      #pragma unroll
      for (int ni = 0; ni < 4; ++ni)
        acc[mi][ni] = __builtin_amdgcn_mfma_f32_16x16x32_bf16(
            af[mi], bfr[ni], acc[mi][ni], 0, 0, 0);
  }

  #pragma unroll
  for (int mi = 0; mi < 4; ++mi) {
    #pragma unroll
    for (int ni = 0; ni < 4; ++ni) {
      const int col = colbase + wc * 64 + ni * 16 + ml;
      const float bv = bias[col];
      #pragma unroll
      for (int r = 0; r < 4; ++r) {
        const int row = rowbase + wr * 64 + mi * 16 + q * 4 + r;
        const float val = acc[mi][ni][r] + bv;
        if (BF16OUT)
          ((unsigned short*)Cv)[(size_t)row * N + col] = f2bf(val);
        else
          ((float*)Cv)[(size_t)row * N + col] = val;
      }
    }
  }
}

// ---------------------------------------------------------------------------
// Residue-class flash attention. One wave per (bh, slot), slot -> (r, g)
// via closed form: g = slot/p, r = slot%p, valid iff g < ceil(L_r/16).
// Max needed slot over p in [1,63] is 189 < 192 (worst at p=63).
//  S^T = K . Q^T via mfma 16x16x32; softmax per column (q = lane&15);
//  P^T C-layout -> B-operand layout via 8 shfl + 4 selects; O^T += V^T . P^T.
// ---------------------------------------------------------------------------
__global__ __launch_bounds__(64)
void attn_flash(const unsigned short* __restrict__ qkv,
                const int* __restrict__ periods,
                unsigned short* __restrict__ ao) {
  const int bh = blockIdx.x, slot = blockIdx.y;
  int p = periods[bh]; if (p < 1) p = 1;
  const int qt = slot / p;
  const int r  = slot - qt * p;
  const int L  = (T_ - 1 - r) / p + 1;
  if (qt >= ((L + 15) >> 4)) return;
  const int b = bh >> 3, h = bh & 7;
  const int q0 = qt << 4;
  const int nq = min(16, L - q0);
  const int Nk = min(L, q0 + 16);          // keys needed by this q-tile

  const int lane = threadIdx.x;
  const int Q = lane >> 4, c = lane & 15;

  __shared__ unsigned short Qs[16 * 72];   // stride 72 halfs (144 B, 16B-aligned)
  __shared__ unsigned short Ks[32 * 72];
  __shared__ unsigned short Vs[32 * 70];   // stride 70 (b32 writes; u16 reads conflict-free)

  const size_t rowb = (size_t)b * T_ * QKVS + (size_t)h * HD_;

  // ---- stage Q tile (16 rows x 64 halfs), 2 b128 per lane ----
  {
    const int u = lane >> 2, ch3 = lane & 3;
    const int t = q0 + min(u, nq - 1);     // clamp (dup row; unused cols masked)
    const unsigned short* g = qkv + rowb + (size_t)(r + t * p) * QKVS + ch3 * 16;
    int4 v0 = ((const int4*)g)[0];
    int4 v1 = ((const int4*)g)[1];
    *(int4*)&Qs[u * 72 + ch3 * 16 + 0] = v0;
    *(int4*)&Qs[u * 72 + ch3 * 16 + 8] = v1;
  }
  __syncthreads();
  bf16x8 qf[2];                            // B-frag: B[k=d=Q*8+j+32hf][n=q=c]
  qf[0] = *(const bf16x8*)&Qs[c * 72 + Q * 8];
  qf[1] = *(const bf16x8*)&Qs[c * 72 + Q * 8 + 32];

  float m_run = -3.0e38f, l_run = 0.f;
  f32x4 o[4] = {};
  const size_t kb = rowb + D_;
  const size_t vb = rowb + 2 * D_;
  const int kap = lane >> 1, ke = lane & 1;

  for (int k0 = 0; k0 < Nk; k0 += 32) {
    // ---- stage K,V tile (32 rows x 64 halfs each) ----
    {
      const int t = min(k0 + kap, Nk - 1); // clamp (dups masked by causal cond)
      const unsigned short* gk = qkv + kb + (size_t)(r + t * p) * QKVS + ke * 32;
      const unsigned short* gv = qkv + vb + (size_t)(r + t * p) * QKVS + ke * 32;
      int4 a0 = ((const int4*)gk)[0], a1 = ((const int4*)gk)[1],
           a2 = ((const int4*)gk)[2], a3 = ((const int4*)gk)[3];
      int4 b0 = ((const int4*)gv)[0], b1 = ((const int4*)gv)[1],
           b2 = ((const int4*)gv)[2], b3 = ((const int4*)gv)[3];
      __syncthreads();                     // prev iter's frag reads complete
      *(int4*)&Ks[kap * 72 + ke * 32 + 0]  = a0;
      *(int4*)&Ks[kap * 72 + ke * 32 + 8]  = a1;
      *(int4*)&Ks[kap * 72 + ke * 32 + 16] = a2;
      *(int4*)&Ks[kap * 72 + ke * 32 + 24] = a3;
      unsigned int* vw = (unsigned int*)Vs + kap * 35 + ke * 16;
      int4 bb[4] = {b0, b1, b2, b3};
      #pragma unroll
      for (int i = 0; i < 4; ++i) {
        vw[i * 4 + 0] = bb[i].x; vw[i * 4 + 1] = bb[i].y;
        vw[i * 4 + 2] = bb[i].z; vw[i * 4 + 3] = bb[i].w;
      }
      __syncthreads();
    }

    // ---- S^T = K . Q^T  (two 16-key M-tiles, K-depth 64 = 2 chained) ----
    f32x4 s[2];
    #pragma unroll
    for (int mt = 0; mt < 2; ++mt) {
      bf16x8 a0 = *(const bf16x8*)&Ks[(mt * 16 + c) * 72 + Q * 8];
      bf16x8 a1 = *(const bf16x8*)&Ks[(mt * 16 + c) * 72 + Q * 8 + 32];
      f32x4 acc = {};
      acc = __builtin_amdgcn_mfma_f32_16x16x32_bf16(a0, qf[0], acc, 0, 0, 0);
      acc = __builtin_amdgcn_mfma_f32_16x16x32_bf16(a1, qf[1], acc, 0, 0, 0);
      s[mt] = acc;
    }

    // ---- scale + causal mask + online softmax (per col q=c) ----
    float pvv[8];
    float tmax = -3.0e38f;
    #pragma unroll
    for (int mt = 0; mt < 2; ++mt)
      #pragma unroll
      for (int rg = 0; rg < 4; ++rg) {
        const int kk = k0 + mt * 16 + Q * 4 + rg;   // key t-index
        float v = s[mt][rg] * 0.125f;               // 1/sqrt(HD)
        v = (kk <= q0 + c) ? v : -3.0e38f;          // causal in t-space
        pvv[mt * 4 + rg] = v;
        tmax = fmaxf(tmax, v);
      }
    tmax = fmaxf(tmax, __shfl_xor(tmax, 16));
    tmax = fmaxf(tmax, __shfl_xor(tmax, 32));
    const float m_new = fmaxf(m_run, tmax);
    const float alpha = __expf(m_run - m_new);
    float tsum = 0.f;
    #pragma unroll
    for (int i = 0; i < 8; ++i) { pvv[i] = __expf(pvv[i] - m_new); tsum += pvv[i]; }
    tsum += __shfl_xor(tsum, 16);
    tsum += __shfl_xor(tsum, 32);
    l_run = l_run * alpha + tsum;
    m_run = m_new;

    // ---- P^T: C-layout -> B-operand layout (8 shfl + 4 selects) ----
    unsigned int pk0[2], pk1[2];
    pk0[0] = pack2bf(pvv[0], pvv[1]); pk0[1] = pack2bf(pvv[2], pvv[3]);
    pk1[0] = pack2bf(pvv[4], pvv[5]); pk1[1] = pack2bf(pvv[6], pvv[7]);
    int dw[4];
    const int sq2 = (Q & 1) << 1;
    #pragma unroll
    for (int d = 0; d < 4; ++d) {
      const int src = ((sq2 + (d >> 1)) << 4) + c;
      const int v0 = __shfl((int)pk0[d & 1], src);
      const int v1 = __shfl((int)pk1[d & 1], src);
      dw[d] = (Q >= 2) ? v1 : v0;
    }
    int4 bi = make_int4(dw[0], dw[1], dw[2], dw[3]);
    bf16x8 pb = *(bf16x8*)&bi;

    // ---- O^T += V^T . P^T  (4 d-chunks of 16) ----
    #pragma unroll
    for (int ch = 0; ch < 4; ++ch) {
      unsigned short vh[8];
      #pragma unroll
      for (int j = 0; j < 8; ++j)
        vh[j] = Vs[(Q * 8 + j) * 70 + ch * 16 + c];
      unsigned int vi[4];
      #pragma unroll
      for (int j = 0; j < 4; ++j)
        vi[j] = (unsigned int)vh[2 * j] | ((unsigned int)vh[2 * j + 1] << 16);
      int4 ai4 = make_int4((int)vi[0], (int)vi[1], (int)vi[2], (int)vi[3]);
      bf16x8 af = *(bf16x8*)&ai4;
      f32x4 oo = o[ch];
      #pragma unroll
      for (int t2 = 0; t2 < 4; ++t2) oo[t2] *= alpha;
      o[ch] = __builtin_amdgcn_mfma_f32_16x16x32_bf16(af, pb, oo, 0, 0, 0);
    }
  }

  // ---- epilogue: O[q][d] = O^T[d][q] / l ----
  if (c < nq) {
    const float invl = 1.f / l_run;
    const int gq = r + (q0 + c) * p;
    unsigned int* dst =
        (unsigned int*)(ao + (size_t)(b * T_ + gq) * D_ + h * HD_);
    #pragma unroll
    for (int ch = 0; ch < 4; ++ch)
      #pragma unroll
      for (int rp = 0; rp < 2; ++rp) {
        const int dhalf = ch * 16 + Q * 4 + rp * 2;   // even
        dst[dhalf >> 1] =
            pack2bf(o[ch][rp * 2] * invl, o[ch][rp * 2 + 1] * invl);
      }
  }
}

// ---------------------------------------------------------------------------
extern "C" void kernel_launch(void* const* d_in, const int* in_sizes, int n_in,
                              void* d_out, int out_size, void* d_ws, size_t ws_size,
                              hipStream_t stream) {
  const float* x      = (const float*)d_in[0];   // (B,T,D)
  const int*   period = (const int*)  d_in[1];   // (B,H)
  const float* w_qkv  = (const float*)d_in[2];   // (3D, D)
  const float* b_qkv  = (const float*)d_in[3];   // (3D,)
  const float* w_out  = (const float*)d_in[4];   // (D, D)
  const float* b_out  = (const float*)d_in[5];   // (D,)
  float* out = (float*)d_out;                    // (B,T,D)

  const int M = B_ * T_;                         // 4096

  // ws layout (bytes):
  //   [0,    4 MB) xb (x bf16)         -- reused as aob after GEMM1
  //   [4,  5.5 MB) wqb (w_qkv bf16)
  //   [5.5,  6 MB) wob (w_out bf16)
  //   [6,   18 MB) qkvb bf16 (4096 x 1536)
  char* ws = (char*)d_ws;
  unsigned short* xb   = (unsigned short*)(ws);
  unsigned short* wqb  = (unsigned short*)(ws + (size_t)M * D_ * 2);
  unsigned short* wob  = (unsigned short*)(ws + (size_t)M * D_ * 2
                                              + (size_t)QKVS * D_ * 2);
  unsigned short* qkvb = (unsigned short*)(ws + (size_t)M * D_ * 2
                                              + (size_t)QKVS * D_ * 2
                                              + (size_t)D_ * D_ * 2);
  unsigned short* aob  = xb;   // alias: x_bf16 dead after GEMM1

  // input casts
  cast_f32_bf16<<<dim3((M * D_ / 4 + 255) / 256), dim3(256), 0, stream>>>(
      x, xb, M * D_ / 4);
  cast_f32_bf16<<<dim3((QKVS * D_ / 4 + 255) / 256), dim3(256), 0, stream>>>(
      w_qkv, wqb, QKVS * D_ / 4);
  cast_f32_bf16<<<dim3((D_ * D_ / 4 + 255) / 256), dim3(256), 0, stream>>>(
      w_out, wob, D_ * D_ / 4);

  // 1) QKV projection -> bf16 qkv  (128x128 tile, grid 12x32 = 384)
  gemm_nt_mfma128<1><<<dim3(QKVS / 128, M / 128), dim3(256), 0, stream>>>(
      xb, wqb, b_qkv, qkvb, M, QKVS, D_);

  // 2) residue-class flash attention -> aob (bf16); slot map computed inline
  attn_flash<<<dim3(16, 192), dim3(64), 0, stream>>>(qkvb, period, aob);

  // 3) output projection -> fp32 out (128x64 tile, grid 8x32 = 256 = 1/CU)
  gemm_nt_mfma<0><<<dim3(D_ / 64, M / 128), dim3(256), 0, stream>>>(
      aob, wob, b_out, out, M, D_, D_);
}

// Round 5
// 116.637 us; speedup vs baseline: 2.8544x; 1.0767x over previous
//
#include <hip/hip_runtime.h>
#include <math.h>

#define B_  2
#define T_  2048
#define D_  512
#define H_  8
#define HD_ 64
#define QKVS (3*D_)   // 1536 halfs, row stride of fused qkv buffer

typedef __bf16 bf16x8 __attribute__((ext_vector_type(8)));
typedef float  f32x4  __attribute__((ext_vector_type(4)));

__device__ inline unsigned short f2bf(float f) {   // RN-even fp32->bf16
  unsigned int u = __float_as_uint(f);
  return (unsigned short)((u + 0x7FFFu + ((u >> 16) & 1u)) >> 16);
}
__device__ inline unsigned int pack2bf(float lo, float hi) {
  return (unsigned int)f2bf(lo) | ((unsigned int)f2bf(hi) << 16);
}

// ---------------------------------------------------------------------------
// Fused cast fp32 -> bf16 for x, w_qkv, w_out in one launch (float4 units).
// ---------------------------------------------------------------------------
__global__ void cast_all(const float* __restrict__ x,
                         const float* __restrict__ wq,
                         const float* __restrict__ wo,
                         unsigned short* __restrict__ xb,
                         unsigned short* __restrict__ wqb,
                         unsigned short* __restrict__ wob) {
  const int n_x  = (B_ * T_ * D_) / 4;
  const int n_wq = (QKVS * D_) / 4;
  const int n_wo = (D_ * D_) / 4;
  int i = blockIdx.x * blockDim.x + threadIdx.x;
  const float* src; unsigned short* dst; int off;
  if (i < n_x)                { src = x;  dst = xb;  off = i; }
  else if (i < n_x + n_wq)    { src = wq; dst = wqb; off = i - n_x; }
  else if (i < n_x + n_wq + n_wo) { src = wo; dst = wob; off = i - n_x - n_wq; }
  else return;
  float4 v = ((const float4*)src)[off];
  ushort4 o;
  o.x = f2bf(v.x); o.y = f2bf(v.y); o.z = f2bf(v.z); o.w = f2bf(v.w);
  ((ushort4*)dst)[off] = o;
}

// ---------------------------------------------------------------------------
// MFMA bf16 GEMM (NT), 128x64 tile: 4 waves, each 64x32 = 4x2 accs.
// Used for the out-projection (N=512 -> grid 256 = 1 block/CU, balanced).
// ---------------------------------------------------------------------------
template<int BF16OUT>
__global__ __launch_bounds__(256)
void gemm_nt_mfma(const unsigned short* __restrict__ A,
                  const unsigned short* __restrict__ Bw,
                  const float* __restrict__ bias, void* __restrict__ Cv,
                  int M, int N, int K) {
  __shared__ short Asd[128 * 32];
  __shared__ short Bsd[64 * 32];

  const int tid = threadIdx.x;
  const int w   = tid >> 6;
  const int l   = tid & 63;
  const int wr  = w >> 1;
  const int wc  = w & 1;
  const int q   = l >> 4;
  const int ml  = l & 15;
  const int arow = l >> 2;
  const int kch  = (l & 3) * 8;

  const int rowbase = blockIdx.y * 128;
  const int colbase = blockIdx.x * 64;

  f32x4 acc[4][2] = {};

  for (int k0 = 0; k0 < K; k0 += 32) {
    __syncthreads();
    #pragma unroll
    for (int s = 0; s < 2; ++s) {
      const unsigned short* g =
          A + (size_t)(rowbase + s * 64 + w * 16 + arow) * K + k0 + kch;
      short* lp = &Asd[s * 2048 + w * 512];
      __builtin_amdgcn_global_load_lds(
          (const __attribute__((address_space(1))) void*)g,
          (__attribute__((address_space(3))) void*)lp, 16, 0, 0);
    }
    {
      const unsigned short* g =
          Bw + (size_t)(colbase + w * 16 + arow) * K + k0 + kch;
      short* lp = &Bsd[w * 512];
      __builtin_amdgcn_global_load_lds(
          (const __attribute__((address_space(1))) void*)g,
          (__attribute__((address_space(3))) void*)lp, 16, 0, 0);
    }
    __syncthreads();

    bf16x8 af[4], bfr[2];
    #pragma unroll
    for (int mi = 0; mi < 4; ++mi)
      af[mi] = *(const bf16x8*)&Asd[(wr * 64 + mi * 16 + ml) * 32 + q * 8];
    #pragma unroll
    for (int ni = 0; ni < 2; ++ni)
      bfr[ni] = *(const bf16x8*)&Bsd[(wc * 32 + ni * 16 + ml) * 32 + q * 8];
    #pragma unroll
    for (int mi = 0; mi < 4; ++mi)
      #pragma unroll
      for (int ni = 0; ni < 2; ++ni)
        acc[mi][ni] = __builtin_amdgcn_mfma_f32_16x16x32_bf16(
            af[mi], bfr[ni], acc[mi][ni], 0, 0, 0);
  }

  #pragma unroll
  for (int mi = 0; mi < 4; ++mi) {
    #pragma unroll
    for (int ni = 0; ni < 2; ++ni) {
      const int col = colbase + wc * 32 + ni * 16 + ml;
      const float bv = bias[col];
      #pragma unroll
      for (int r = 0; r < 4; ++r) {
        const int row = rowbase + wr * 64 + mi * 16 + q * 4 + r;
        const float val = acc[mi][ni][r] + bv;
        if (BF16OUT)
          ((unsigned short*)Cv)[(size_t)row * N + col] = f2bf(val);
        else
          ((float*)Cv)[(size_t)row * N + col] = val;
      }
    }
  }
}

// ---------------------------------------------------------------------------
// MFMA bf16 GEMM (NT), 128x128 tile: 4 waves (2x2), each 64x64 = 4x4 accs.
// Used for QKV projection.
// ---------------------------------------------------------------------------
template<int BF16OUT>
__global__ __launch_bounds__(256)
void gemm_nt_mfma128(const unsigned short* __restrict__ A,
                     const unsigned short* __restrict__ Bw,
                     const float* __restrict__ bias, void* __restrict__ Cv,
                     int M, int N, int K) {
  __shared__ short Asd[128 * 32];   // 8 KB
  __shared__ short Bsd[128 * 32];   // 8 KB

  const int tid = threadIdx.x;
  const int w   = tid >> 6;
  const int l   = tid & 63;
  const int wr  = w >> 1;
  const int wc  = w & 1;
  const int q   = l >> 4;
  const int ml  = l & 15;
  const int arow = l >> 2;
  const int kch  = (l & 3) * 8;

  const int rowbase = blockIdx.y * 128;
  const int colbase = blockIdx.x * 128;

  f32x4 acc[4][4] = {};

  for (int k0 = 0; k0 < K; k0 += 32) {
    __syncthreads();
    #pragma unroll
    for (int s = 0; s < 2; ++s) {
      const unsigned short* ga =
          A + (size_t)(rowbase + s * 64 + w * 16 + arow) * K + k0 + kch;
      __builtin_amdgcn_global_load_lds(
          (const __attribute__((address_space(1))) void*)ga,
          (__attribute__((address_space(3))) void*)&Asd[s * 2048 + w * 512],
          16, 0, 0);
      const unsigned short* gb =
          Bw + (size_t)(colbase + s * 64 + w * 16 + arow) * K + k0 + kch;
      __builtin_amdgcn_global_load_lds(
          (const __attribute__((address_space(1))) void*)gb,
          (__attribute__((address_space(3))) void*)&Bsd[s * 2048 + w * 512],
          16, 0, 0);
    }
    __syncthreads();

    bf16x8 af[4], bfr[4];
    #pragma unroll
    for (int mi = 0; mi < 4; ++mi)
      af[mi] = *(const bf16x8*)&Asd[(wr * 64 + mi * 16 + ml) * 32 + q * 8];
    #pragma unroll
    for (int ni = 0; ni < 4; ++ni)
      bfr[ni] = *(const bf16x8*)&Bsd[(wc * 64 + ni * 16 + ml) * 32 + q * 8];
    #pragma unroll
    for (int mi = 0; mi < 4; ++mi)
      #pragma unroll
      for (int ni = 0; ni < 4; ++ni)
        acc[mi][ni] = __builtin_amdgcn_mfma_f32_16x16x32_bf16(
            af[mi], bfr[ni], acc[mi][ni], 0, 0, 0);
  }

  #pragma unroll
  for (int mi = 0; mi < 4; ++mi) {
    #pragma unroll
    for (int ni = 0; ni < 4; ++ni) {
      const int col = colbase + wc * 64 + ni * 16 + ml;
      const float bv = bias[col];
      #pragma unroll
      for (int r = 0; r < 4; ++r) {
        const int row = rowbase + wr * 64 + mi * 16 + q * 4 + r;
        const float val = acc[mi][ni][r] + bv;
        if (BF16OUT)
          ((unsigned short*)Cv)[(size_t)row * N + col] = f2bf(val);
        else
          ((float*)Cv)[(size_t)row * N + col] = val;
      }
    }
  }
}

// ---------------------------------------------------------------------------
// Residue-class flash attention, 64-query stripes.
// Block = (bh, slot); slot -> (g = slot/p, r = slot%p); stripe = queries
// [g*64, g*64+64) of residue r's subsequence (token t -> r + t*p).
// 4 waves share the staged 32-key K/V tiles (key sets are nested across the
// stripe's q-tiles -> 4x staging reuse vs one-wave-per-16-queries).
// V is staged TRANSPOSED in LDS (Vt[d][key], stride 40 halfs) so the PV
// A-fragment is a single ds_read_b128 per 16-d chunk (no u16 gather+pack).
// Max needed slot over p in [1,63] is 62 -> grid y = 63.
// ---------------------------------------------------------------------------
__global__ __launch_bounds__(256)
void attn_flash2(const unsigned short* __restrict__ qkv,
                 const int* __restrict__ periods,
                 unsigned short* __restrict__ ao) {
  const int bh = blockIdx.x, slot = blockIdx.y;
  int p = periods[bh]; if (p < 1) p = 1;
  const int g  = slot / p;
  const int r  = slot - g * p;
  const int L  = (T_ - 1 - r) / p + 1;   // tokens in this residue class
  const int q0 = g << 6;                 // stripe base (t-space)
  if (q0 >= L) return;
  const int b = bh >> 3, h = bh & 7;
  const int Lrem = L - q0;               // >= 1
  const int Nkb  = min(L, q0 + 64);      // keys needed by the whole block

  const int tid  = threadIdx.x;
  const int w    = tid >> 6;             // wave 0..3
  const int lane = tid & 63;
  const int Q = lane >> 4, c = lane & 15;

  __shared__ __align__(16) unsigned short Qs[64 * 72];  // 9216 B
  __shared__ __align__(16) unsigned short Ks[32 * 72];  // 4608 B
  __shared__ __align__(16) unsigned short Vt[64 * 40];  // 5120 B, [d][key]

  const size_t rowb = (size_t)b * T_ * QKVS + (size_t)h * HD_;

  // ---- stage Q stripe (64 rows x 64 halfs): 32 B per thread ----
  {
    const int u = tid >> 2, ch4 = (tid & 3) * 16;
    const int t = q0 + min(u, Lrem - 1);            // clamp (dup row, masked)
    const unsigned short* gq = qkv + rowb + (size_t)(r + t * p) * QKVS + ch4;
    int4 v0 = ((const int4*)gq)[0];
    int4 v1 = ((const int4*)gq)[1];
    *(int4*)&Qs[u * 72 + ch4 + 0] = v0;
    *(int4*)&Qs[u * 72 + ch4 + 8] = v1;
  }
  __syncthreads();
  bf16x8 qf[2];                          // B-frag: B[k=d=Q*8+j(+32)][n=q=c]
  qf[0] = *(const bf16x8*)&Qs[(w * 16 + c) * 72 + Q * 8];
  qf[1] = *(const bf16x8*)&Qs[(w * 16 + c) * 72 + Q * 8 + 32];

  const int qb      = w * 16;            // wave's query offset in stripe
  const int nqw     = min(16, Lrem - qb);// <=0 -> inactive wave (barriers only)
  const int qglob   = q0 + qb + c;       // this lane's query t-index
  const int mylastk = q0 + qb + 15;      // last key this wave can need

  float m_run = -3.0e38f, l_run = 0.f;
  f32x4 o[4] = {};
  const size_t kb = rowb + D_;
  const size_t vb = rowb + 2 * D_;

  // staging assignments (256 threads)
  const int krow = tid >> 3, koff = (tid & 7) * 8;      // K: 16B/thread
  const int vkey = tid & 31, vd0 = (tid >> 5) * 8;      // V: 16B/thread

  for (int k0 = 0; k0 < Nkb; k0 += 32) {
    // ---- stage K (row-major) + V (transposed) 32-key tiles ----
    {
      const int tk = min(k0 + krow, Nkb - 1);           // dup rows masked below
      const int tv = min(k0 + vkey, Nkb - 1);
      int4 kv = *(const int4*)(qkv + kb + (size_t)(r + tk * p) * QKVS + koff);
      int4 vv = *(const int4*)(qkv + vb + (size_t)(r + tv * p) * QKVS + vd0);
      unsigned short vh[8];
      *(int4*)vh = vv;
      __syncthreads();                   // prev iter's frag reads complete
      *(int4*)&Ks[krow * 72 + koff] = kv;
      #pragma unroll
      for (int j = 0; j < 8; ++j)
        Vt[(vd0 + j) * 40 + vkey] = vh[j];
      __syncthreads();
    }

    if (nqw > 0 && k0 <= mylastk) {
      // ---- S^T = K . Q^T  (two 16-key M-tiles, K-depth 64) ----
      f32x4 s[2];
      #pragma unroll
      for (int mt = 0; mt < 2; ++mt) {
        bf16x8 a0 = *(const bf16x8*)&Ks[(mt * 16 + c) * 72 + Q * 8];
        bf16x8 a1 = *(const bf16x8*)&Ks[(mt * 16 + c) * 72 + Q * 8 + 32];
        f32x4 acc = {};
        acc = __builtin_amdgcn_mfma_f32_16x16x32_bf16(a0, qf[0], acc, 0, 0, 0);
        acc = __builtin_amdgcn_mfma_f32_16x16x32_bf16(a1, qf[1], acc, 0, 0, 0);
        s[mt] = acc;
      }

      // ---- scale + causal mask + online softmax (per col q=c) ----
      float pvv[8];
      float tmax = -3.0e38f;
      #pragma unroll
      for (int mt = 0; mt < 2; ++mt)
        #pragma unroll
        for (int rg = 0; rg < 4; ++rg) {
          const int kk = k0 + mt * 16 + Q * 4 + rg;     // key t-index
          float v = s[mt][rg] * 0.125f;                 // 1/sqrt(HD)
          v = (kk <= qglob) ? v : -3.0e38f;
          pvv[mt * 4 + rg] = v;
          tmax = fmaxf(tmax, v);
        }
      tmax = fmaxf(tmax, __shfl_xor(tmax, 16));
      tmax = fmaxf(tmax, __shfl_xor(tmax, 32));
      const float m_new = fmaxf(m_run, tmax);
      const float alpha = __expf(m_run - m_new);
      float tsum = 0.f;
      #pragma unroll
      for (int i = 0; i < 8; ++i) { pvv[i] = __expf(pvv[i] - m_new); tsum += pvv[i]; }
      tsum += __shfl_xor(tsum, 16);
      tsum += __shfl_xor(tsum, 32);
      l_run = l_run * alpha + tsum;
      m_run = m_new;

      // ---- P^T: C-layout -> B-operand layout (8 shfl + 4 selects) ----
      unsigned int pk0[2], pk1[2];
      pk0[0] = pack2bf(pvv[0], pvv[1]); pk0[1] = pack2bf(pvv[2], pvv[3]);
      pk1[0] = pack2bf(pvv[4], pvv[5]); pk1[1] = pack2bf(pvv[6], pvv[7]);
      int dw[4];
      const int sq2 = (Q & 1) << 1;
      #pragma unroll
      for (int d = 0; d < 4; ++d) {
        const int src = ((sq2 + (d >> 1)) << 4) + c;
        const int v0 = __shfl((int)pk0[d & 1], src);
        const int v1 = __shfl((int)pk1[d & 1], src);
        dw[d] = (Q >= 2) ? v1 : v0;
      }
      int4 bi = make_int4(dw[0], dw[1], dw[2], dw[3]);
      bf16x8 pb = *(bf16x8*)&bi;

      // ---- O^T += V^T . P^T  (4 d-chunks; A-frag = one b128 from Vt) ----
      #pragma unroll
      for (int ch = 0; ch < 4; ++ch) {
        bf16x8 af = *(const bf16x8*)&Vt[(ch * 16 + c) * 40 + Q * 8];
        f32x4 oo = o[ch];
        #pragma unroll
        for (int t2 = 0; t2 < 4; ++t2) oo[t2] *= alpha;
        o[ch] = __builtin_amdgcn_mfma_f32_16x16x32_bf16(af, pb, oo, 0, 0, 0);
      }
    }
  }

  // ---- epilogue: O[q][d] = O^T[d][q] / l ----
  if (nqw > 0 && c < nqw) {
    const float invl = 1.f / l_run;
    const int tok = r + (q0 + qb + c) * p;
    unsigned int* dst =
        (unsigned int*)(ao + (size_t)(b * T_ + tok) * D_ + h * HD_);
    #pragma unroll
    for (int ch = 0; ch < 4; ++ch)
      #pragma unroll
      for (int rp = 0; rp < 2; ++rp) {
        const int dhalf = ch * 16 + Q * 4 + rp * 2;   // even
        dst[dhalf >> 1] =
            pack2bf(o[ch][rp * 2] * invl, o[ch][rp * 2 + 1] * invl);
      }
  }
}

// ---------------------------------------------------------------------------
extern "C" void kernel_launch(void* const* d_in, const int* in_sizes, int n_in,
                              void* d_out, int out_size, void* d_ws, size_t ws_size,
                              hipStream_t stream) {
  const float* x      = (const float*)d_in[0];   // (B,T,D)
  const int*   period = (const int*)  d_in[1];   // (B,H)
  const float* w_qkv  = (const float*)d_in[2];   // (3D, D)
  const float* b_qkv  = (const float*)d_in[3];   // (3D,)
  const float* w_out  = (const float*)d_in[4];   // (D, D)
  const float* b_out  = (const float*)d_in[5];   // (D,)
  float* out = (float*)d_out;                    // (B,T,D)

  const int M = B_ * T_;                         // 4096

  // ws layout (bytes):
  //   [0,    4 MB) xb (x bf16)         -- reused as aob after GEMM1
  //   [4,  5.5 MB) wqb (w_qkv bf16)
  //   [5.5,  6 MB) wob (w_out bf16)
  //   [6,   18 MB) qkvb bf16 (4096 x 1536)
  char* ws = (char*)d_ws;
  unsigned short* xb   = (unsigned short*)(ws);
  unsigned short* wqb  = (unsigned short*)(ws + (size_t)M * D_ * 2);
  unsigned short* wob  = (unsigned short*)(ws + (size_t)M * D_ * 2
                                              + (size_t)QKVS * D_ * 2);
  unsigned short* qkvb = (unsigned short*)(ws + (size_t)M * D_ * 2
                                              + (size_t)QKVS * D_ * 2
                                              + (size_t)D_ * D_ * 2);
  unsigned short* aob  = xb;   // alias: x_bf16 dead after GEMM1

  // fused input casts (786432 float4 groups -> 3072 blocks)
  {
    const int n4 = (M * D_ + QKVS * D_ + D_ * D_) / 4;
    cast_all<<<dim3((n4 + 255) / 256), dim3(256), 0, stream>>>(
        x, w_qkv, w_out, xb, wqb, wob);
  }

  // 1) QKV projection -> bf16 qkv  (128x128 tile, grid 12x32 = 384)
  gemm_nt_mfma128<1><<<dim3(QKVS / 128, M / 128), dim3(256), 0, stream>>>(
      xb, wqb, b_qkv, qkvb, M, QKVS, D_);

  // 2) residue-class flash attention (64-query stripes) -> aob (bf16)
  attn_flash2<<<dim3(16, 63), dim3(256), 0, stream>>>(qkvb, period, aob);

  // 3) output projection -> fp32 out (128x64 tile, grid 8x32 = 256 = 1/CU)
  gemm_nt_mfma<0><<<dim3(D_ / 64, M / 128), dim3(256), 0, stream>>>(
      aob, wob, b_out, out, M, D_, D_);
}